// Round 1
// baseline (1959.113 us; speedup 1.0000x reference)
//
#include <hip/hip_runtime.h>

#define D 64

// ---------------------------------------------------------------------------
// Scatter SPMM: for each edge e, acc[rows[e]] += vals[e] * ebs[cols[e]]
// 16 threads per edge, each handling a float4 (4 dims). Both Laplacians
// fused into one launch (items [0,E) -> LI, [E,2E) -> L).
// unsafeAtomicAdd -> global_atomic_add_f32 (no CAS loop).
// ---------------------------------------------------------------------------
__global__ void scatter_kernel(
    const float* __restrict__ LI_vals, const int* __restrict__ LI_rows, const int* __restrict__ LI_cols,
    const float* __restrict__ L_vals,  const int* __restrict__ L_rows,  const int* __restrict__ L_cols,
    const float* __restrict__ ebs,
    float* __restrict__ accLI, float* __restrict__ accL, int E)
{
    long long t = (long long)blockIdx.x * blockDim.x + threadIdx.x;
    long long e2 = t >> 4;              // edge index in [0, 2E)
    if (e2 >= 2LL * E) return;
    int c = ((int)t & 15) << 2;         // dim offset (float4 granularity)

    const float* vals; const int* rows; const int* cols; float* acc; int e;
    if (e2 < E) { vals = LI_vals; rows = LI_rows; cols = LI_cols; acc = accLI; e = (int)e2; }
    else        { vals = L_vals;  rows = L_rows;  cols = L_cols;  acc = accL;  e = (int)(e2 - E); }

    float v  = vals[e];
    int   r  = rows[e];
    int   cl = cols[e];

    const float4 x = *(const float4*)(ebs + (size_t)cl * D + c);
    float* o = acc + (size_t)r * D + c;
    unsafeAtomicAdd(o + 0, v * x.x);
    unsafeAtomicAdd(o + 1, v * x.y);
    unsafeAtomicAdd(o + 2, v * x.z);
    unsafeAtomicAdd(o + 3, v * x.w);
}

// ---------------------------------------------------------------------------
// Epilogue: out = leaky_relu(LI_side @ W_side + (L_side * entity) @ W_dot)
// One wave per 64-row tile. Lane j owns row tile*64+j: its A-row and B-row
// live in registers (64+64 VGPRs); W matrices are read from LDS with
// wave-uniform addresses (broadcast, conflict-free). VALU-bound by design.
// ---------------------------------------------------------------------------
__global__ __launch_bounds__(256) void epilogue_kernel(
    const float* __restrict__ accLI, const float* __restrict__ accL,
    const float* __restrict__ entity,
    const float* __restrict__ W_side, const float* __restrict__ W_dot,
    float* __restrict__ out, int n)
{
    __shared__ float ws[D * D];
    __shared__ float wd[D * D];
    for (int idx = threadIdx.x; idx < D * D; idx += 256) {
        ws[idx] = W_side[idx];
        wd[idx] = W_dot[idx];
    }
    __syncthreads();

    int lane   = threadIdx.x & 63;
    int wave   = (blockIdx.x << 2) | (threadIdx.x >> 6);
    int nWaves = gridDim.x << 2;
    int nTiles = (n + 63) >> 6;

    for (int tile = wave; tile < nTiles; tile += nWaves) {
        int row = (tile << 6) + lane;
        bool valid = row < n;

        float a[D], b[D];
        if (valid) {
            const float4* ap = (const float4*)(accLI  + (size_t)row * D);
            const float4* lp = (const float4*)(accL   + (size_t)row * D);
            const float4* ep = (const float4*)(entity + (size_t)row * D);
#pragma unroll
            for (int q = 0; q < 16; ++q) {
                float4 av = ap[q];
                float4 lv = lp[q];
                float4 ev = ep[q];
                a[4*q+0] = av.x; a[4*q+1] = av.y; a[4*q+2] = av.z; a[4*q+3] = av.w;
                b[4*q+0] = lv.x * ev.x; b[4*q+1] = lv.y * ev.y;
                b[4*q+2] = lv.z * ev.z; b[4*q+3] = lv.w * ev.w;
            }
        } else {
#pragma unroll
            for (int q = 0; q < D; ++q) { a[q] = 0.f; b[q] = 0.f; }
        }

        float4* op = (float4*)(out + (size_t)row * D);
        for (int jc = 0; jc < 16; ++jc) {
            float acc0 = 0.f, acc1 = 0.f, acc2 = 0.f, acc3 = 0.f;
#pragma unroll
            for (int k = 0; k < D; ++k) {
                float4 w1 = *(const float4*)(ws + k * D + (jc << 2));
                float4 w2 = *(const float4*)(wd + k * D + (jc << 2));
                acc0 += a[k] * w1.x + b[k] * w2.x;
                acc1 += a[k] * w1.y + b[k] * w2.y;
                acc2 += a[k] * w1.z + b[k] * w2.z;
                acc3 += a[k] * w1.w + b[k] * w2.w;
            }
            float4 r;
            r.x = acc0 > 0.f ? acc0 : 0.2f * acc0;
            r.y = acc1 > 0.f ? acc1 : 0.2f * acc1;
            r.z = acc2 > 0.f ? acc2 : 0.2f * acc2;
            r.w = acc3 > 0.f ? acc3 : 0.2f * acc3;
            if (valid) op[jc] = r;
        }
    }
}

extern "C" void kernel_launch(void* const* d_in, const int* in_sizes, int n_in,
                              void* d_out, int out_size, void* d_ws, size_t ws_size,
                              hipStream_t stream) {
    const float* ebs     = (const float*)d_in[0];
    const float* entity  = (const float*)d_in[1];
    const float* W_side  = (const float*)d_in[2];
    const float* W_dot   = (const float*)d_in[3];
    const float* LI_vals = (const float*)d_in[4];
    const float* L_vals  = (const float*)d_in[5];
    const int*   LI_rows = (const int*)d_in[6];
    const int*   LI_cols = (const int*)d_in[7];
    const int*   L_rows  = (const int*)d_in[8];
    const int*   L_cols  = (const int*)d_in[9];
    float* out = (float*)d_out;

    int E = in_sizes[4];
    int n = in_sizes[0] / D;

    float* accLI = (float*)d_ws;
    float* accL  = accLI + (size_t)n * D;

    // Zero the accumulators (d_ws is re-poisoned to 0xAA before every launch).
    hipMemsetAsync(d_ws, 0, (size_t)2 * n * D * sizeof(float), stream);

    long long totalThreads = 2LL * E * 16;
    int sblocks = (int)((totalThreads + 255) / 256);
    scatter_kernel<<<sblocks, 256, 0, stream>>>(
        LI_vals, LI_rows, LI_cols, L_vals, L_rows, L_cols, ebs, accLI, accL, E);

    int nTiles  = (n + 63) / 64;
    int eblocks = (nTiles + 3) / 4;
    epilogue_kernel<<<eblocks, 256, 0, stream>>>(
        accLI, accL, entity, W_side, W_dot, out, n);
}

// Round 2
// 576.228 us; speedup vs baseline: 3.3999x; 3.3999x over previous
//
#include <hip/hip_runtime.h>

#define D   64
#define CAP 32   // bucket capacity per row; Poisson(10) => P(deg>=32) ~ 2.6e-9

// ---------------------------------------------------------------------------
// Phase 1: expand edges into per-row buckets. One thread per edge.
// slot = atomicAdd(cnt[row]) (int atomic, cheap); store packed (col,val).
// Overflow (essentially never) falls back to direct fp32 atomics into acc.
// ---------------------------------------------------------------------------
__global__ __launch_bounds__(256) void expand_kernel(
    const float* __restrict__ LI_vals, const int* __restrict__ LI_rows, const int* __restrict__ LI_cols,
    const float* __restrict__ L_vals,  const int* __restrict__ L_rows,  const int* __restrict__ L_cols,
    const float* __restrict__ ebs,
    int* __restrict__ cnt, uint2* __restrict__ buckets, float* __restrict__ acc,
    int E, int N)
{
    int t = blockIdx.x * 256 + threadIdx.x;
    if (t >= 2 * E) return;
    int m = (t >= E) ? 1 : 0;
    int e = t - m * E;
    const float* vals = m ? L_vals : LI_vals;
    const int*   rows = m ? L_rows : LI_rows;
    const int*   cols = m ? L_cols : LI_cols;

    int   r  = rows[e];
    int   cl = cols[e];
    float v  = vals[e];
    int   g  = m * N + r;

    int slot = atomicAdd(cnt + g, 1);
    if (slot < CAP) {
        buckets[(size_t)g * CAP + slot] = make_uint2((unsigned)cl, __float_as_uint(v));
    } else {
        // overflow fallback: direct atomic accumulate (rare to nonexistent)
        float* o = acc + (size_t)g * D;
        const float* x = ebs + (size_t)cl * D;
#pragma unroll
        for (int q = 0; q < D; ++q) unsafeAtomicAdd(o + q, v * x[q]);
    }
}

// ---------------------------------------------------------------------------
// Phase 2: gather-reduce per row. 16 lanes per row-slot (4 rows per wave);
// lane l owns dims [4l, 4l+4). Bucket pair loads are group-uniform
// (broadcast); ebs row reads are 256 B contiguous per group. One plain
// float4 store per lane at the end -- zero fp32 atomics.
// ---------------------------------------------------------------------------
__global__ __launch_bounds__(256) void gather_kernel(
    const uint2* __restrict__ buckets, const int* __restrict__ cnt,
    const float* __restrict__ ebs, float* __restrict__ acc, int twoN)
{
    int g = (blockIdx.x * 256 + threadIdx.x) >> 4;
    if (g >= twoN) return;
    int l = threadIdx.x & 15;

    int c  = cnt[g];
    int mm = c < CAP ? c : CAP;
    const uint2* bk = buckets + (size_t)g * CAP;

    float4 s = make_float4(0.f, 0.f, 0.f, 0.f);
    for (int i = 0; i < mm; ++i) {
        uint2 p = bk[i];                       // same addr across the 16 lanes
        float v = __uint_as_float(p.y);
        const float4 x = *(const float4*)(ebs + (size_t)p.x * D + (l << 2));
        s.x += v * x.x; s.y += v * x.y; s.z += v * x.z; s.w += v * x.w;
    }

    float4* o = (float4*)(acc + (size_t)g * D) + l;
    if (c > CAP) {                             // merge overflow contribution
        float4 base = *o;
        s.x += base.x; s.y += base.y; s.z += base.z; s.w += base.w;
    }
    *o = s;
}

// ---------------------------------------------------------------------------
// Epilogue: out = leaky_relu(LI_side @ W_side + (L_side * entity) @ W_dot)
// One wave per 64-row tile; lane j owns row tile*64+j. W matrices are read
// with wave-uniform indices straight from global => scalar (s_load) path on
// the scalar pipe, leaving VALU free for pure FMA.
// ---------------------------------------------------------------------------
__global__ __launch_bounds__(256) void epilogue_kernel(
    const float* __restrict__ acc, const float* __restrict__ entity,
    const float* __restrict__ W_side, const float* __restrict__ W_dot,
    float* __restrict__ out, int n)
{
    int lane = threadIdx.x & 63;
    int wave = (blockIdx.x << 2) | (threadIdx.x >> 6);
    int row  = (wave << 6) + lane;
    bool valid = row < n;

    const float* accLI = acc;
    const float* accL  = acc + (size_t)n * D;

    float a[D], b[D];
    if (valid) {
        const float4* ap = (const float4*)(accLI  + (size_t)row * D);
        const float4* lp = (const float4*)(accL   + (size_t)row * D);
        const float4* ep = (const float4*)(entity + (size_t)row * D);
#pragma unroll
        for (int q = 0; q < 16; ++q) {
            float4 av = ap[q];
            float4 lv = lp[q];
            float4 ev = ep[q];
            a[4*q+0] = av.x; a[4*q+1] = av.y; a[4*q+2] = av.z; a[4*q+3] = av.w;
            b[4*q+0] = lv.x * ev.x; b[4*q+1] = lv.y * ev.y;
            b[4*q+2] = lv.z * ev.z; b[4*q+3] = lv.w * ev.w;
        }
    } else {
#pragma unroll
        for (int q = 0; q < D; ++q) { a[q] = 0.f; b[q] = 0.f; }
    }

    float4* op = (float4*)(out + (size_t)row * D);
#pragma unroll 1
    for (int jc = 0; jc < 16; ++jc) {
        float acc0 = 0.f, acc1 = 0.f, acc2 = 0.f, acc3 = 0.f;
#pragma unroll
        for (int k = 0; k < D; ++k) {
            float4 w1 = *(const float4*)(W_side + (k << 6) + (jc << 2)); // uniform -> s_load
            float4 w2 = *(const float4*)(W_dot  + (k << 6) + (jc << 2));
            acc0 += a[k] * w1.x + b[k] * w2.x;
            acc1 += a[k] * w1.y + b[k] * w2.y;
            acc2 += a[k] * w1.z + b[k] * w2.z;
            acc3 += a[k] * w1.w + b[k] * w2.w;
        }
        float4 r;
        r.x = acc0 > 0.f ? acc0 : 0.2f * acc0;
        r.y = acc1 > 0.f ? acc1 : 0.2f * acc1;
        r.z = acc2 > 0.f ? acc2 : 0.2f * acc2;
        r.w = acc3 > 0.f ? acc3 : 0.2f * acc3;
        if (valid) op[jc] = r;
    }
}

// ---------------------------------------------------------------------------
// Fallback (R1 path) if workspace is too small for buckets: direct atomics.
// ---------------------------------------------------------------------------
__global__ void scatter_kernel(
    const float* __restrict__ LI_vals, const int* __restrict__ LI_rows, const int* __restrict__ LI_cols,
    const float* __restrict__ L_vals,  const int* __restrict__ L_rows,  const int* __restrict__ L_cols,
    const float* __restrict__ ebs,
    float* __restrict__ accLI, float* __restrict__ accL, int E)
{
    long long t = (long long)blockIdx.x * blockDim.x + threadIdx.x;
    long long e2 = t >> 4;
    if (e2 >= 2LL * E) return;
    int c = ((int)t & 15) << 2;

    const float* vals; const int* rows; const int* cols; float* acc; int e;
    if (e2 < E) { vals = LI_vals; rows = LI_rows; cols = LI_cols; acc = accLI; e = (int)e2; }
    else        { vals = L_vals;  rows = L_rows;  cols = L_cols;  acc = accL;  e = (int)(e2 - E); }

    float v  = vals[e];
    int   r  = rows[e];
    int   cl = cols[e];

    const float4 x = *(const float4*)(ebs + (size_t)cl * D + c);
    float* o = acc + (size_t)r * D + c;
    unsafeAtomicAdd(o + 0, v * x.x);
    unsafeAtomicAdd(o + 1, v * x.y);
    unsafeAtomicAdd(o + 2, v * x.z);
    unsafeAtomicAdd(o + 3, v * x.w);
}

extern "C" void kernel_launch(void* const* d_in, const int* in_sizes, int n_in,
                              void* d_out, int out_size, void* d_ws, size_t ws_size,
                              hipStream_t stream) {
    const float* ebs     = (const float*)d_in[0];
    const float* entity  = (const float*)d_in[1];
    const float* W_side  = (const float*)d_in[2];
    const float* W_dot   = (const float*)d_in[3];
    const float* LI_vals = (const float*)d_in[4];
    const float* L_vals  = (const float*)d_in[5];
    const int*   LI_rows = (const int*)d_in[6];
    const int*   LI_cols = (const int*)d_in[7];
    const int*   L_rows  = (const int*)d_in[8];
    const int*   L_cols  = (const int*)d_in[9];
    float* out = (float*)d_out;

    int E = in_sizes[4];
    int n = in_sizes[0] / D;

    size_t cntBytes = (size_t)2 * n * sizeof(int);             // 0.8 MB
    size_t accBytes = (size_t)2 * n * D * sizeof(float);       // 51.2 MB
    size_t bktBytes = (size_t)2 * n * CAP * sizeof(uint2);     // 51.2 MB
    size_t need = cntBytes + accBytes + bktBytes;

    int nTiles  = (n + 63) / 64;
    int eblocks = (nTiles + 3) / 4;

    if (ws_size >= need) {
        int*   cnt     = (int*)d_ws;
        float* acc     = (float*)((char*)d_ws + cntBytes);
        uint2* buckets = (uint2*)((char*)d_ws + cntBytes + accBytes);

        // zero counters + accumulators (acc zero needed only for overflow path)
        hipMemsetAsync(d_ws, 0, cntBytes + accBytes, stream);

        int xblocks = (2 * E + 255) / 256;
        expand_kernel<<<xblocks, 256, 0, stream>>>(
            LI_vals, LI_rows, LI_cols, L_vals, L_rows, L_cols, ebs,
            cnt, buckets, acc, E, n);

        int twoN = 2 * n;
        int gblocks = (twoN * 16 + 255) / 256;
        gather_kernel<<<gblocks, 256, 0, stream>>>(buckets, cnt, ebs, acc, twoN);

        epilogue_kernel<<<eblocks, 256, 0, stream>>>(
            acc, entity, W_side, W_dot, out, n);
    } else {
        // R1 fallback: direct fp32 atomics
        float* acc   = (float*)d_ws;
        float* accLI = acc;
        float* accL  = accLI + (size_t)n * D;
        hipMemsetAsync(d_ws, 0, accBytes, stream);

        long long totalThreads = 2LL * E * 16;
        int sblocks = (int)((totalThreads + 255) / 256);
        scatter_kernel<<<sblocks, 256, 0, stream>>>(
            LI_vals, LI_rows, LI_cols, L_vals, L_rows, L_cols, ebs, accLI, accL, E);

        epilogue_kernel<<<eblocks, 256, 0, stream>>>(
            acc, entity, W_side, W_dot, out, n);
    }
}

// Round 3
// 335.638 us; speedup vs baseline: 5.8370x; 1.7168x over previous
//
#include <hip/hip_runtime.h>

#define D   64
#define CAP 32   // bucket capacity per row; Poisson(10) => P(deg>=32) ~ 2.6e-9

typedef __attribute__((ext_vector_type(8))) short short8;
typedef __attribute__((ext_vector_type(4))) float floatx4;

__device__ __forceinline__ unsigned short f2bf(float f) {
    unsigned u = __float_as_uint(f);
    u += 0x7fffu + ((u >> 16) & 1u);   // RNE
    return (unsigned short)(u >> 16);
}

// ---------------------------------------------------------------------------
// Phase 1: expand edges into per-row buckets. One thread per edge.
// ---------------------------------------------------------------------------
__global__ __launch_bounds__(256) void expand_kernel(
    const float* __restrict__ LI_vals, const int* __restrict__ LI_rows, const int* __restrict__ LI_cols,
    const float* __restrict__ L_vals,  const int* __restrict__ L_rows,  const int* __restrict__ L_cols,
    const float* __restrict__ ebs,
    int* __restrict__ cnt, uint2* __restrict__ buckets, float* __restrict__ acc,
    int E, int N)
{
    int t = blockIdx.x * 256 + threadIdx.x;
    if (t >= 2 * E) return;
    int m = (t >= E) ? 1 : 0;
    int e = t - m * E;
    const float* vals = m ? L_vals : LI_vals;
    const int*   rows = m ? L_rows : LI_rows;
    const int*   cols = m ? L_cols : LI_cols;

    int   r  = rows[e];
    int   cl = cols[e];
    float v  = vals[e];
    int   g  = m * N + r;

    int slot = atomicAdd(cnt + g, 1);
    if (slot < CAP) {
        buckets[(size_t)g * CAP + slot] = make_uint2((unsigned)cl, __float_as_uint(v));
    } else {
        float* o = acc + (size_t)g * D;
        const float* x = ebs + (size_t)cl * D;
#pragma unroll
        for (int q = 0; q < D; ++q) unsafeAtomicAdd(o + q, v * x[q]);
    }
}

// ---------------------------------------------------------------------------
// Phase 2: gather-reduce per row. 16 lanes per row; one plain store at end.
// ---------------------------------------------------------------------------
__global__ __launch_bounds__(256) void gather_kernel(
    const uint2* __restrict__ buckets, const int* __restrict__ cnt,
    const float* __restrict__ ebs, float* __restrict__ acc, int twoN)
{
    int g = (blockIdx.x * 256 + threadIdx.x) >> 4;
    if (g >= twoN) return;
    int l = threadIdx.x & 15;

    int c  = cnt[g];
    int mm = c < CAP ? c : CAP;
    const uint2* bk = buckets + (size_t)g * CAP;

    float4 s = make_float4(0.f, 0.f, 0.f, 0.f);
    for (int i = 0; i < mm; ++i) {
        uint2 p = bk[i];
        float v = __uint_as_float(p.y);
        const float4 x = *(const float4*)(ebs + (size_t)p.x * D + (l << 2));
        s.x += v * x.x; s.y += v * x.y; s.z += v * x.z; s.w += v * x.w;
    }

    float4* o = (float4*)(acc + (size_t)g * D) + l;
    if (c > CAP) {
        float4 base = *o;
        s.x += base.x; s.y += base.y; s.z += base.z; s.w += base.w;
    }
    *o = s;
}

// ---------------------------------------------------------------------------
// Prep: pack [Ws;Wd] (K=128, 64 cols) into bf16 MFMA B-fragment layout.
// Fragment f = jt*4+kt (jt: 16-col tile, kt: 32-k step). Lane l, j=0..7:
//   k = kt*32 + (l>>4)*8 + j, n = jt*16 + (l&15)
// stored at Wfrag[f*512 + l*8 + j]  -> each wave's frag load is 16 B/lane
// contiguous.
// ---------------------------------------------------------------------------
__global__ __launch_bounds__(256) void wfrag_kernel(
    const float* __restrict__ W_side, const float* __restrict__ W_dot,
    unsigned short* __restrict__ Wfrag)
{
    int t = blockIdx.x * 256 + threadIdx.x;   // 0..1023
    int f = t >> 6;                            // fragment 0..15
    int l = t & 63;                            // lane
    int jt = f >> 2, kt = f & 3;
    int q = l >> 4, nl = l & 15;
    int n = jt * 16 + nl;
#pragma unroll
    for (int j = 0; j < 8; ++j) {
        int k = kt * 32 + q * 8 + j;
        float w = (k < 64) ? W_side[k * 64 + n] : W_dot[(k - 64) * 64 + n];
        Wfrag[(size_t)f * 512 + l * 8 + j] = f2bf(w);
    }
}

// ---------------------------------------------------------------------------
// Epilogue via MFMA: out = leaky_relu([A | B] @ [Ws; Wd]), K=128, bf16 in /
// fp32 accum. Block = 64 rows, 4 waves x 16 rows. A|B staged in LDS as bf16
// with row stride 136 (pad breaks 256B-stride bank conflicts).
// ---------------------------------------------------------------------------
#define ABSTRIDE 136
__global__ __launch_bounds__(256) void epilogue_mfma_kernel(
    const float* __restrict__ acc, const float* __restrict__ entity,
    const unsigned short* __restrict__ Wfrag,
    float* __restrict__ out, int n)
{
    __shared__ unsigned short ab[64 * ABSTRIDE];
    int t = threadIdx.x;
    int rowbase = blockIdx.x * 64;
    const float* accLI = acc;
    const float* accL  = acc + (size_t)n * D;

    // Stage 64 rows x 128 bf16 ([a(64) | b(64)]) into LDS.
#pragma unroll
    for (int iter = 0; iter < 4; ++iter) {
        int idx = iter * 256 + t;      // 0..1023
        int row = idx >> 4;            // 0..63
        int p8  = idx & 15;            // which 8-float chunk of the 128
        int grow = rowbase + row;
        float4 v0, v1;
        if (grow < n) {
            if (p8 < 8) {
                const float4* src = (const float4*)(accLI + (size_t)grow * D + p8 * 8);
                v0 = src[0]; v1 = src[1];
            } else {
                const float4* ls = (const float4*)(accL   + (size_t)grow * D + (p8 - 8) * 8);
                const float4* es = (const float4*)(entity + (size_t)grow * D + (p8 - 8) * 8);
                float4 l0 = ls[0], l1 = ls[1], e0 = es[0], e1 = es[1];
                v0 = make_float4(l0.x * e0.x, l0.y * e0.y, l0.z * e0.z, l0.w * e0.w);
                v1 = make_float4(l1.x * e1.x, l1.y * e1.y, l1.z * e1.z, l1.w * e1.w);
            }
        } else {
            v0 = make_float4(0.f, 0.f, 0.f, 0.f);
            v1 = v0;
        }
        unsigned short* dst = ab + row * ABSTRIDE + p8 * 8;
        short8 pk;
        pk[0] = (short)f2bf(v0.x); pk[1] = (short)f2bf(v0.y);
        pk[2] = (short)f2bf(v0.z); pk[3] = (short)f2bf(v0.w);
        pk[4] = (short)f2bf(v1.x); pk[5] = (short)f2bf(v1.y);
        pk[6] = (short)f2bf(v1.z); pk[7] = (short)f2bf(v1.w);
        *(short8*)dst = pk;
    }
    __syncthreads();

    int w = t >> 6;      // wave 0..3: rows [w*16, w*16+16)
    int l = t & 63;
    int q = l >> 4, m = l & 15;

    floatx4 accv[4];
#pragma unroll
    for (int jt = 0; jt < 4; ++jt) accv[jt] = (floatx4){0.f, 0.f, 0.f, 0.f};

#pragma unroll
    for (int kt = 0; kt < 4; ++kt) {
        // A-frag: A[m][k], m = l&15 (row within wave tile), k = kt*32+q*8+j
        const short8 a = *(const short8*)(ab + (w * 16 + m) * ABSTRIDE + kt * 32 + q * 8);
#pragma unroll
        for (int jt = 0; jt < 4; ++jt) {
            const short8 b = *(const short8*)(Wfrag + (size_t)(jt * 4 + kt) * 512 + l * 8);
            accv[jt] = __builtin_amdgcn_mfma_f32_16x16x32_bf16(a, b, accv[jt], 0, 0, 0);
        }
    }

    // C/D layout: col = l&15, row_in_tile = q*4 + reg
#pragma unroll
    for (int jt = 0; jt < 4; ++jt) {
#pragma unroll
        for (int r = 0; r < 4; ++r) {
            int grow = rowbase + w * 16 + q * 4 + r;
            if (grow < n) {
                float v = accv[jt][r];
                v = v > 0.f ? v : 0.2f * v;
                out[(size_t)grow * D + jt * 16 + m] = v;
            }
        }
    }
}

// ---------------------------------------------------------------------------
// fp32 fallback epilogue (only used if workspace too small for buckets).
// ---------------------------------------------------------------------------
__global__ __launch_bounds__(256) void epilogue_kernel(
    const float* __restrict__ acc, const float* __restrict__ entity,
    const float* __restrict__ W_side, const float* __restrict__ W_dot,
    float* __restrict__ out, int n)
{
    int lane = threadIdx.x & 63;
    int wave = (blockIdx.x << 2) | (threadIdx.x >> 6);
    int row  = (wave << 6) + lane;
    bool valid = row < n;

    const float* accLI = acc;
    const float* accL  = acc + (size_t)n * D;

    float a[D], b[D];
    if (valid) {
        const float4* ap = (const float4*)(accLI  + (size_t)row * D);
        const float4* lp = (const float4*)(accL   + (size_t)row * D);
        const float4* ep = (const float4*)(entity + (size_t)row * D);
#pragma unroll
        for (int qq = 0; qq < 16; ++qq) {
            float4 av = ap[qq]; float4 lv = lp[qq]; float4 ev = ep[qq];
            a[4*qq+0] = av.x; a[4*qq+1] = av.y; a[4*qq+2] = av.z; a[4*qq+3] = av.w;
            b[4*qq+0] = lv.x * ev.x; b[4*qq+1] = lv.y * ev.y;
            b[4*qq+2] = lv.z * ev.z; b[4*qq+3] = lv.w * ev.w;
        }
    } else {
#pragma unroll
        for (int qq = 0; qq < D; ++qq) { a[qq] = 0.f; b[qq] = 0.f; }
    }

    float4* op = (float4*)(out + (size_t)row * D);
#pragma unroll 1
    for (int jc = 0; jc < 16; ++jc) {
        float acc0 = 0.f, acc1 = 0.f, acc2 = 0.f, acc3 = 0.f;
#pragma unroll
        for (int k = 0; k < D; ++k) {
            float4 w1 = *(const float4*)(W_side + (k << 6) + (jc << 2));
            float4 w2 = *(const float4*)(W_dot  + (k << 6) + (jc << 2));
            acc0 += a[k] * w1.x + b[k] * w2.x;
            acc1 += a[k] * w1.y + b[k] * w2.y;
            acc2 += a[k] * w1.z + b[k] * w2.z;
            acc3 += a[k] * w1.w + b[k] * w2.w;
        }
        float4 r;
        r.x = acc0 > 0.f ? acc0 : 0.2f * acc0;
        r.y = acc1 > 0.f ? acc1 : 0.2f * acc1;
        r.z = acc2 > 0.f ? acc2 : 0.2f * acc2;
        r.w = acc3 > 0.f ? acc3 : 0.2f * acc3;
        if (valid) op[jc] = r;
    }
}

__global__ void scatter_kernel(
    const float* __restrict__ LI_vals, const int* __restrict__ LI_rows, const int* __restrict__ LI_cols,
    const float* __restrict__ L_vals,  const int* __restrict__ L_rows,  const int* __restrict__ L_cols,
    const float* __restrict__ ebs,
    float* __restrict__ accLI, float* __restrict__ accL, int E)
{
    long long t = (long long)blockIdx.x * blockDim.x + threadIdx.x;
    long long e2 = t >> 4;
    if (e2 >= 2LL * E) return;
    int c = ((int)t & 15) << 2;

    const float* vals; const int* rows; const int* cols; float* acc; int e;
    if (e2 < E) { vals = LI_vals; rows = LI_rows; cols = LI_cols; acc = accLI; e = (int)e2; }
    else        { vals = L_vals;  rows = L_rows;  cols = L_cols;  acc = accL;  e = (int)(e2 - E); }

    float v  = vals[e];
    int   r  = rows[e];
    int   cl = cols[e];

    const float4 x = *(const float4*)(ebs + (size_t)cl * D + c);
    float* o = acc + (size_t)r * D + c;
    unsafeAtomicAdd(o + 0, v * x.x);
    unsafeAtomicAdd(o + 1, v * x.y);
    unsafeAtomicAdd(o + 2, v * x.z);
    unsafeAtomicAdd(o + 3, v * x.w);
}

extern "C" void kernel_launch(void* const* d_in, const int* in_sizes, int n_in,
                              void* d_out, int out_size, void* d_ws, size_t ws_size,
                              hipStream_t stream) {
    const float* ebs     = (const float*)d_in[0];
    const float* entity  = (const float*)d_in[1];
    const float* W_side  = (const float*)d_in[2];
    const float* W_dot   = (const float*)d_in[3];
    const float* LI_vals = (const float*)d_in[4];
    const float* L_vals  = (const float*)d_in[5];
    const int*   LI_rows = (const int*)d_in[6];
    const int*   LI_cols = (const int*)d_in[7];
    const int*   L_rows  = (const int*)d_in[8];
    const int*   L_cols  = (const int*)d_in[9];
    float* out = (float*)d_out;

    int E = in_sizes[4];
    int n = in_sizes[0] / D;

    size_t cntBytes  = (size_t)2 * n * sizeof(int);            // 0.8 MB
    size_t accBytes  = (size_t)2 * n * D * sizeof(float);      // 51.2 MB
    size_t bktBytes  = (size_t)2 * n * CAP * sizeof(uint2);    // 51.2 MB
    size_t wfBytes   = (size_t)16 * 512 * sizeof(unsigned short); // 16 KB
    size_t need = cntBytes + accBytes + bktBytes + wfBytes;

    if (ws_size >= need) {
        int*   cnt     = (int*)d_ws;
        float* acc     = (float*)((char*)d_ws + cntBytes);
        uint2* buckets = (uint2*)((char*)d_ws + cntBytes + accBytes);
        unsigned short* Wfrag = (unsigned short*)((char*)d_ws + cntBytes + accBytes + bktBytes);

        hipMemsetAsync(d_ws, 0, cntBytes + accBytes, stream);

        int xblocks = (2 * E + 255) / 256;
        expand_kernel<<<xblocks, 256, 0, stream>>>(
            LI_vals, LI_rows, LI_cols, L_vals, L_rows, L_cols, ebs,
            cnt, buckets, acc, E, n);

        wfrag_kernel<<<4, 256, 0, stream>>>(W_side, W_dot, Wfrag);

        int twoN = 2 * n;
        int gblocks = (twoN * 16 + 255) / 256;
        gather_kernel<<<gblocks, 256, 0, stream>>>(buckets, cnt, ebs, acc, twoN);

        int eblocks = (n + 63) / 64;
        epilogue_mfma_kernel<<<eblocks, 256, 0, stream>>>(
            acc, entity, Wfrag, out, n);
    } else {
        float* acc   = (float*)d_ws;
        float* accLI = acc;
        float* accL  = accLI + (size_t)n * D;
        hipMemsetAsync(d_ws, 0, accBytes, stream);

        long long totalThreads = 2LL * E * 16;
        int sblocks = (int)((totalThreads + 255) / 256);
        scatter_kernel<<<sblocks, 256, 0, stream>>>(
            LI_vals, LI_rows, LI_cols, L_vals, L_rows, L_cols, ebs, accLI, accL, E);

        int nTiles  = (n + 63) / 64;
        int feblocks = (nTiles + 3) / 4;
        epilogue_kernel<<<feblocks, 256, 0, stream>>>(
            acc, entity, W_side, W_dot, out, n);
    }
}